// Round 2
// baseline (8017.723 us; speedup 1.0000x reference)
//
#include <hip/hip_runtime.h>

// CGIterator: N=50000, K=128, I=4 chained CG iterations, fp32.
// Round 2: packed-fp32 (v_pk_fma_f32) restructure.
//  - linear_in : thread = (node = tid>>6, 4 cols = 4*(tid&63)); A via wave-uniform
//                ds_read_b128, W via global dwordx4, acc as float2 pairs.
//  - tp        : thread = (2 nodes, 2 cols), packed over the column pair.
//  - linear_out: thread = (node, 2 cols), results routed back through s_h,
//                then skip-added by the f-register owners.

#define NNODES 50000
#define KCH 128
#define PCH 256
#define NITER 4
#define NB 4

typedef __attribute__((ext_vector_type(2))) float v2f;
typedef __attribute__((ext_vector_type(4))) float v4f;

static __device__ __forceinline__ v2f splat2(float x) { return (v2f){x, x}; }

#if __has_builtin(__builtin_elementwise_fma)
static __device__ __forceinline__ v2f pk_fma(v2f a, v2f b, v2f c) {
    return __builtin_elementwise_fma(a, b, c);
}
#else
static __device__ __forceinline__ v2f pk_fma(v2f a, v2f b, v2f c) {
    v2f r; r.x = __builtin_fmaf(a.x, b.x, c.x); r.y = __builtin_fmaf(a.y, b.y, c.y);
    return r;
}
#endif

__global__ __launch_bounds__(256, 2)
void cg_fused(const float* __restrict__ f0,
              const float* __restrict__ f1,
              const float* __restrict__ f2,
              const float* __restrict__ Uin,
              const float* __restrict__ gamma,
              const float* __restrict__ W_in,
              const float* __restrict__ W_out,
              float* __restrict__ out)
{
    __shared__ float sUp[45][12];        // symmetrized U, padded for b128
    __shared__ float s_h[NB][9][KCH];    // RMS-normed feats; reused as linear_out result
    __shared__ float s_hc[NB][9][PCH];   // hc, overwritten in place by tp

    const int tid = threadIdx.x;
    const int node0 = blockIdx.x * NB;

    // ---- build symmetrized padded U in LDS (once per block)
    for (int idx = tid; idx < 45 * 12; idx += 256) {
        const int ab = idx / 12;
        const int c  = idx % 12;
        int a = 0, r = ab;
        while (r >= 9 - a) { r -= 9 - a; ++a; }
        const int b = a + r;
        float v = 0.0f;
        if (c < 9) {
            v = Uin[(a * 9 + b) * 9 + c];
            if (a != b) v += Uin[(b * 9 + a) * 9 + c];
        }
        sUp[ab][c] = v;
    }

    const int kk = tid & (KCH - 1);   // channel 0..127   (RMS/skip/IO ownership)
    const int nh = tid >> 7;          // node-half 0/1
    const int ng = tid >> 6;          // node group 0..3  (linear_in / linear_out)
    const int c0 = tid & 63;          // col group

    // ---- load initial feats: thread owns nodes 2*nh+{0,1}, channel kk, all m
    float f[2][9];
    #pragma unroll
    for (int j = 0; j < 2; ++j) {
        const int n = node0 + 2 * nh + j;
        f[j][0] = f0[n * KCH + kk];
        #pragma unroll
        for (int m = 0; m < 3; ++m) f[j][1 + m] = f1[(n * 3 + m) * KCH + kk];
        #pragma unroll
        for (int m = 0; m < 5; ++m) f[j][4 + m] = f2[(n * 5 + m) * KCH + kk];
    }

    #pragma unroll 1
    for (int it = 0; it < NITER; ++it) {
        // ================= phase A: equivariant RMS norm -> s_h =================
        {
            const float g0 = gamma[(it * 3 + 0) * KCH + kk];
            const float g1 = gamma[(it * 3 + 1) * KCH + kk];
            const float g2 = gamma[(it * 3 + 2) * KCH + kk];
            #pragma unroll
            for (int j = 0; j < 2; ++j) {
                const int nl = 2 * nh + j;
                const float s0 = f[j][0] * f[j][0];
                const float s1 = f[j][1] * f[j][1] + f[j][2] * f[j][2] + f[j][3] * f[j][3];
                const float s2 = f[j][4] * f[j][4] + f[j][5] * f[j][5] + f[j][6] * f[j][6]
                               + f[j][7] * f[j][7] + f[j][8] * f[j][8];
                const float r0 = rsqrtf(s0 + 1e-6f) * g0;
                const float r1 = rsqrtf(s1 * (1.0f / 3.0f) + 1e-6f) * g1;
                const float r2 = rsqrtf(s2 * (1.0f / 5.0f) + 1e-6f) * g2;
                s_h[nl][0][kk] = f[j][0] * r0;
                s_h[nl][1][kk] = f[j][1] * r1;
                s_h[nl][2][kk] = f[j][2] * r1;
                s_h[nl][3][kk] = f[j][3] * r1;
                s_h[nl][4][kk] = f[j][4] * r2;
                s_h[nl][5][kk] = f[j][5] * r2;
                s_h[nl][6][kk] = f[j][6] * r2;
                s_h[nl][7][kk] = f[j][7] * r2;
                s_h[nl][8][kk] = f[j][8] * r2;
            }
        }
        __syncthreads();  // B1

        // ================= phase B: linear_in (node ng, cols 4c0..4c0+3) ========
        {
            const float* __restrict__ Wb0 = W_in + (size_t)(it * 3 + 0) * KCH * PCH + 4 * c0;
            const float* __restrict__ Wb1 = W_in + (size_t)(it * 3 + 1) * KCH * PCH + 4 * c0;
            const float* __restrict__ Wb2 = W_in + (size_t)(it * 3 + 2) * KCH * PCH + 4 * c0;
            v2f acc[9][2];
            #pragma unroll
            for (int m = 0; m < 9; ++m) { acc[m][0] = (v2f)0.0f; acc[m][1] = (v2f)0.0f; }

            #pragma unroll 2
            for (int kc = 0; kc < KCH; kc += 4) {
                v4f A[9];
                #pragma unroll
                for (int m = 0; m < 9; ++m) A[m] = *(const v4f*)&s_h[ng][m][kc];
                #pragma unroll
                for (int ks = 0; ks < 4; ++ks) {
                    const int k = kc + ks;
                    const v4f w0 = *(const v4f*)(Wb0 + (size_t)k * PCH);
                    const v4f w1 = *(const v4f*)(Wb1 + (size_t)k * PCH);
                    const v4f w2 = *(const v4f*)(Wb2 + (size_t)k * PCH);
                    const v2f w0l = (v2f){w0[0], w0[1]}, w0h = (v2f){w0[2], w0[3]};
                    const v2f w1l = (v2f){w1[0], w1[1]}, w1h = (v2f){w1[2], w1[3]};
                    const v2f w2l = (v2f){w2[0], w2[1]}, w2h = (v2f){w2[2], w2[3]};
                    #pragma unroll
                    for (int m = 0; m < 9; ++m) {
                        const v2f a  = splat2(A[m][ks]);
                        const v2f wl = (m == 0) ? w0l : ((m < 4) ? w1l : w2l);
                        const v2f wh = (m == 0) ? w0h : ((m < 4) ? w1h : w2h);
                        acc[m][0] = pk_fma(a, wl, acc[m][0]);
                        acc[m][1] = pk_fma(a, wh, acc[m][1]);
                    }
                }
            }
            #pragma unroll
            for (int m = 0; m < 9; ++m) {
                const v4f st = (v4f){acc[m][0][0], acc[m][0][1], acc[m][1][0], acc[m][1][1]};
                *(v4f*)&s_hc[ng][m][4 * c0] = st;
            }
        }
        __syncthreads();  // B2

        // ================= phase C: tensor product (2 nodes, col pair) ==========
        {
            const int cp = tid & 127;
            const int np = (tid >> 7) * 2;
            v2f v[2][9];
            #pragma unroll
            for (int j = 0; j < 2; ++j)
                #pragma unroll
                for (int a = 0; a < 9; ++a)
                    v[j][a] = *(const v2f*)&s_hc[np + j][a][2 * cp];

            v2f acc[2][9];
            #pragma unroll
            for (int j = 0; j < 2; ++j)
                #pragma unroll
                for (int c = 0; c < 9; ++c) acc[j][c] = (v2f)0.0f;

            int ab = 0;
            #pragma unroll
            for (int a = 0; a < 9; ++a) {
                #pragma unroll
                for (int b = a; b < 9; ++b) {
                    const v2f q0 = v[0][a] * v[0][b];
                    const v2f q1 = v[1][a] * v[1][b];
                    const v4f U0 = *(const v4f*)&sUp[ab][0];
                    const v4f U1 = *(const v4f*)&sUp[ab][4];
                    const float u8 = sUp[ab][8];
                    #pragma unroll
                    for (int c = 0; c < 4; ++c) {
                        const v2f u = splat2(U0[c]);
                        acc[0][c] = pk_fma(u, q0, acc[0][c]);
                        acc[1][c] = pk_fma(u, q1, acc[1][c]);
                    }
                    #pragma unroll
                    for (int c = 4; c < 8; ++c) {
                        const v2f u = splat2(U1[c - 4]);
                        acc[0][c] = pk_fma(u, q0, acc[0][c]);
                        acc[1][c] = pk_fma(u, q1, acc[1][c]);
                    }
                    {
                        const v2f u = splat2(u8);
                        acc[0][8] = pk_fma(u, q0, acc[0][8]);
                        acc[1][8] = pk_fma(u, q1, acc[1][8]);
                    }
                    ++ab;
                }
            }
            #pragma unroll
            for (int j = 0; j < 2; ++j)
                #pragma unroll
                for (int c = 0; c < 9; ++c)
                    *(v2f*)&s_hc[np + j][c][2 * cp] = acc[j][c];
        }
        __syncthreads();  // B3

        // ================= phase D: linear_out (node ng, cols 2c0,2c0+1) ========
        {
            const float* __restrict__ Vb0 = W_out + (size_t)(it * 3 + 0) * PCH * KCH + 2 * c0;
            const float* __restrict__ Vb1 = W_out + (size_t)(it * 3 + 1) * PCH * KCH + 2 * c0;
            const float* __restrict__ Vb2 = W_out + (size_t)(it * 3 + 2) * PCH * KCH + 2 * c0;
            v2f acc[9];
            #pragma unroll
            for (int m = 0; m < 9; ++m) acc[m] = (v2f)0.0f;

            #pragma unroll 2
            for (int pc = 0; pc < PCH; pc += 4) {
                v4f T[9];
                #pragma unroll
                for (int m = 0; m < 9; ++m) T[m] = *(const v4f*)&s_hc[ng][m][pc];
                #pragma unroll
                for (int ps = 0; ps < 4; ++ps) {
                    const int p = pc + ps;
                    const v2f u0 = *(const v2f*)(Vb0 + (size_t)p * KCH);
                    const v2f u1 = *(const v2f*)(Vb1 + (size_t)p * KCH);
                    const v2f u2 = *(const v2f*)(Vb2 + (size_t)p * KCH);
                    #pragma unroll
                    for (int m = 0; m < 9; ++m) {
                        const v2f w = (m == 0) ? u0 : ((m < 4) ? u1 : u2);
                        acc[m] = pk_fma(splat2(T[m][ps]), w, acc[m]);
                    }
                }
            }
            #pragma unroll
            for (int m = 0; m < 9; ++m)
                *(v2f*)&s_h[ng][m][2 * c0] = acc[m];   // s_h reused as result buffer
        }
        __syncthreads();  // B4

        // ================= phase E: skip connection into f registers ============
        #pragma unroll
        for (int j = 0; j < 2; ++j)
            #pragma unroll
            for (int m = 0; m < 9; ++m)
                f[j][m] += s_h[2 * nh + j][m][kk];
        __syncthreads();  // B5 (next RMS overwrites s_h)
    }

    // ---------- store packed output (N, 9, K)
    #pragma unroll
    for (int j = 0; j < 2; ++j) {
        const int n = node0 + 2 * nh + j;
        #pragma unroll
        for (int m = 0; m < 9; ++m)
            out[(size_t)(n * 9 + m) * KCH + kk] = f[j][m];
    }
}

extern "C" void kernel_launch(void* const* d_in, const int* in_sizes, int n_in,
                              void* d_out, int out_size, void* d_ws, size_t ws_size,
                              hipStream_t stream) {
    const float* f0    = (const float*)d_in[0];
    const float* f1    = (const float*)d_in[1];
    const float* f2    = (const float*)d_in[2];
    const float* U     = (const float*)d_in[3];
    const float* gamma = (const float*)d_in[4];
    const float* W_in  = (const float*)d_in[5];
    const float* W_out = (const float*)d_in[6];
    float* out = (float*)d_out;

    dim3 grid(NNODES / NB);   // 12500
    dim3 block(256);
    hipLaunchKernelGGL(cg_fused, grid, block, 0, stream,
                       f0, f1, f2, U, gamma, W_in, W_out, out);
}